// Round 1
// 268.781 us; speedup vs baseline: 1.0055x; 1.0055x over previous
//
#include <hip/hip_runtime.h>

// Problem: 3x3 VALID conv, NCHW fp32.
// data: [16, 64, 128, 128], weights: [128, 64, 3, 3] -> out [16, 128, 126, 126]
// Strategy: NHWC-bf16 pre-transpose + implicit-GEMM MFMA (16x16x32 bf16),
// m97-style 128co x 128spatial block tile, K = 64ci x 9 taps.
// R1: T2 XOR-swizzle on As/Bs (st_16x32 style). Row stride is 128 B, so the
// unswizzled fragment reads were a 16-way bank conflict (SQ_LDS_BANK_CONFLICT
// = 1.4e7/dispatch ~= 23% of CU cycles). global_load_lds writes linearly, so
// the swizzle is applied by pre-swizzling the per-lane GLOBAL source address
// (rule: linear dest + inverse-swizzled source + swizzled read).

#define BATCH 16
#define CIN   64
#define HIN   128
#define WIN   128
#define COUT  128
#define HO    126
#define WO    126

typedef short bf16x8 __attribute__((ext_vector_type(8)));
typedef float f32x4  __attribute__((ext_vector_type(4)));

__device__ __forceinline__ unsigned short f2bf(float f) {
    union { float f; unsigned int u; } v; v.f = f;
    unsigned int u = v.u;
    unsigned int r = (u + 0x7fffu + ((u >> 16) & 1u)) >> 16;
    return (unsigned short)r;
}

// async global->LDS, 16B per lane. LDS dest = wave-uniform base + lane*16.
__device__ __forceinline__ void async16(const void* g, void* l) {
    __builtin_amdgcn_global_load_lds(
        (const __attribute__((address_space(1))) unsigned int*)(unsigned long long)g,
        (__attribute__((address_space(3))) unsigned int*)(unsigned long long)l,
        16, 0, 0);
}

// ---------- Pre-pass 1: NCHW fp32 -> NHWC bf16 ----------
// grid (2, 128, 16), block 256. Tile: [ci 0..63] x [w0..w0+63] for fixed (b,h).
__global__ __launch_bounds__(256) void t1_nchw_to_nhwc(
        const float* __restrict__ x, unsigned short* __restrict__ y) {
    __shared__ unsigned short tile[64 * 68]; // [w][ci], pad 68 keeps 8B align
    const int b = blockIdx.z, h = blockIdx.y, w0 = blockIdx.x * 64;
    const int t = threadIdx.x;

    const int wl = t & 63, ci0 = t >> 6; // ci0 in 0..3
    const float* src = x + (((size_t)b * CIN) * HIN + h) * WIN + w0 + wl;
#pragma unroll
    for (int j = 0; j < 16; j++) {
        const int ci = ci0 + j * 4;
        tile[wl * 68 + ci] = f2bf(src[(size_t)ci * (HIN * WIN)]);
    }
    __syncthreads();

    const int ci4 = (t & 15) * 4, wl2 = t >> 4; // wl2 in 0..15
#pragma unroll
    for (int j = 0; j < 4; j++) {
        const int w = wl2 + j * 16;
        ushort4 v = *(const ushort4*)&tile[w * 68 + ci4];
        *(ushort4*)&y[(((size_t)b * HIN + h) * WIN + w0 + w) * CIN + ci4] = v;
    }
}

// ---------- Pre-pass 2: weights [co][ci][kh][kw] fp32 -> [kh*3+kw][co][ci] bf16 ----------
__global__ __launch_bounds__(256) void t2_weights(
        const float* __restrict__ w, unsigned short* __restrict__ wt) {
    const int idx = blockIdx.x * 256 + threadIdx.x;
    if (idx < COUT * CIN * 9) {
        const int co = idx / (CIN * 9);
        const int r  = idx % (CIN * 9);
        const int ci = r / 9;
        const int k  = r % 9;
        wt[((size_t)k * COUT + co) * CIN + ci] = f2bf(w[idx]);
    }
}

// ---------- Main: implicit-GEMM MFMA conv ----------
// grid (8 wtiles, 16 htiles, 16 b), block 256 (4 waves in 2x2).
// Block tile: 128 co x (8h x 16w) spatial. K-loop: 9 taps x 64 ci.
__global__ __launch_bounds__(256) void conv_mfma(
        const unsigned short* __restrict__ nhwc,   // [b][h][w][ci] bf16
        const unsigned short* __restrict__ wt,     // [tap][co][ci] bf16
        float* __restrict__ out) {
    __shared__ short As[128 * 64]; // [co][ci] 16 KB, XOR-swizzled rows
    __shared__ short Bs[128 * 64]; // [n=dy*16+dx][ci] 16 KB, XOR-swizzled rows

    const int w0 = blockIdx.x * 16;
    const int h0 = blockIdx.y * 8;
    const int b  = blockIdx.z;
    const int tid = threadIdx.x;
    const int lane = tid & 63, wave = tid >> 6;
    const int wm = wave & 1, wn = wave >> 1;
    const int col = lane & 15, quad = lane >> 4;

    // Swizzle: LDS element at linear byte L holds global byte L ^ ((row&7)<<4)
    // where row = L>>7 (128 B rows). On the staging side row&7 == lane>>3, so
    // the per-lane source offset is lane*16 ^ ((lane>>3)<<4) (stays in-row).
    const int swl = (lane * 16) ^ ((lane >> 3) << 4);
    // On the read side row&7 == col&7 for both A and B fragments (row =
    // base + col with base a multiple of 16). XOR in short units: <<3.
    const int rs = (col & 7) << 3;

    f32x4 acc[4][4] = {};

    for (int t = 0; t < 9; t++) {
        const int kh = t / 3, kw = t % 3;
        if (t) __syncthreads();

        // Stage As: contiguous 16 KB slice of transformed weights (pre-swizzled src).
        {
            const char* src = (const char*)wt + (size_t)t * 16384;
            char* dst = (char*)As;
#pragma unroll
            for (int i = 0; i < 4; i++) {
                const int c = wave * 4 + i;
                async16(src + c * 1024 + swl, dst + c * 1024 + lane * 16);
            }
        }
        // Stage Bs: per dy row, 2048 contiguous bytes (16 w x 64 ci bf16).
        {
#pragma unroll
            for (int i = 0; i < 2; i++) {
                const int dy = wave * 2 + i;
                int h = h0 + dy + kh;
                if (h > HIN - 1) h = HIN - 1; // clamp: feeds only masked outputs
                const char* src = (const char*)nhwc +
                    ((size_t)((b * HIN + h) * WIN + w0 + kw)) * (CIN * 2);
                char* dst = (char*)Bs + dy * 2048;
                async16(src + swl, dst + lane * 16);
                async16(src + 1024 + swl, dst + 1024 + lane * 16);
            }
        }
        __syncthreads(); // compiler emits vmcnt(0) drain before barrier

#pragma unroll
        for (int kk = 0; kk < 2; kk++) {
            const int k0 = kk * 32;
            bf16x8 a[4], bb[4];
#pragma unroll
            for (int mi = 0; mi < 4; mi++)
                a[mi] = *(const bf16x8*)&As[(((wm * 64 + mi * 16 + col) * 64) + k0 + quad * 8) ^ rs];
#pragma unroll
            for (int ni = 0; ni < 4; ni++)
                bb[ni] = *(const bf16x8*)&Bs[(((wn * 64 + ni * 16 + col) * 64) + k0 + quad * 8) ^ rs];
#pragma unroll
            for (int mi = 0; mi < 4; mi++)
#pragma unroll
                for (int ni = 0; ni < 4; ni++)
                    acc[mi][ni] = __builtin_amdgcn_mfma_f32_16x16x32_bf16(
                        a[mi], bb[ni], acc[mi][ni], 0, 0, 0);
        }
    }

    // Epilogue. C/D layout: col(N=spatial)=lane&15, row(M=co)=quad*4+reg.
    const int ow = w0 + col;
#pragma unroll
    for (int ni = 0; ni < 4; ni++) {
        const int oh = h0 + wn * 4 + ni;
        if (oh < HO && ow < WO) {
#pragma unroll
            for (int mi = 0; mi < 4; mi++) {
                const int co = wm * 64 + mi * 16 + quad * 4;
                float* o = out + (((size_t)b * COUT + co) * HO + oh) * WO + ow;
#pragma unroll
                for (int r = 0; r < 4; r++)
                    o[(size_t)r * HO * WO] = acc[mi][ni][r];
            }
        }
    }
}

// ---------- Fallback: direct fp32 conv (if d_ws too small) ----------
__global__ __launch_bounds__(256) void conv_direct(
        const float* __restrict__ x, const float* __restrict__ w,
        float* __restrict__ y) {
    const int idx = blockIdx.x * 256 + threadIdx.x;
    if (idx >= BATCH * COUT * HO * WO) return;
    const int ow = idx % WO;
    int t = idx / WO;
    const int oh = t % HO; t /= HO;
    const int co = t % COUT;
    const int b  = t / COUT;
    float acc = 0.f;
    const float* xb = x + (((size_t)b * CIN) * HIN + oh) * WIN + ow;
    const float* wc = w + (size_t)co * (CIN * 9);
    for (int ci = 0; ci < CIN; ci++) {
#pragma unroll
        for (int kh = 0; kh < 3; kh++)
#pragma unroll
            for (int kw = 0; kw < 3; kw++)
                acc += xb[(size_t)ci * (HIN * WIN) + kh * WIN + kw] * wc[ci * 9 + kh * 3 + kw];
    }
    y[idx] = acc;
}

extern "C" void kernel_launch(void* const* d_in, const int* in_sizes, int n_in,
                              void* d_out, int out_size, void* d_ws, size_t ws_size,
                              hipStream_t stream) {
    const float* data    = (const float*)d_in[0];
    const float* weights = (const float*)d_in[1];
    float* out = (float*)d_out;

    const size_t nhwc_bytes = (size_t)BATCH * HIN * WIN * CIN * 2; // 32 MiB
    const size_t slack = 4096;                                      // halo overflow pad
    const size_t wt_bytes = (size_t)9 * COUT * CIN * 2;             // 144 KiB
    const size_t need = nhwc_bytes + slack + wt_bytes;

    if (ws_size >= need) {
        unsigned short* nhwc = (unsigned short*)d_ws;
        unsigned short* wt   = (unsigned short*)((char*)d_ws + nhwc_bytes + slack);
        t1_nchw_to_nhwc<<<dim3(2, HIN, BATCH), 256, 0, stream>>>(data, nhwc);
        t2_weights<<<(COUT * CIN * 9 + 255) / 256, 256, 0, stream>>>(weights, wt);
        conv_mfma<<<dim3(8, 16, BATCH), 256, 0, stream>>>(nhwc, wt, out);
    } else {
        const int n = BATCH * COUT * HO * WO;
        conv_direct<<<(n + 255) / 256, 256, 0, stream>>>(data, weights, out);
    }
}

// Round 3
// 264.182 us; speedup vs baseline: 1.0230x; 1.0174x over previous
//
#include <hip/hip_runtime.h>

// Problem: 3x3 VALID conv, NCHW fp32.
// data: [16, 64, 128, 128], weights: [128, 64, 3, 3] -> out [16, 128, 126, 126]
// R2 restructure (resubmit after infra failure; source audited for hangs/OOB):
// full-width row tile (1 oh x 126 ow x 128 co per block).
//  - B halo (3 input rows, 48KB contiguous in NHWC) staged ONCE per block,
//    XOR-swizzled; the 9-tap K-loop is then BARRIER-FREE (LDS is read-only).
//  - A (weights, 144KB, L2-hot) loaded per-tap straight into registers,
//    software-pipelined one tap ahead. No A LDS, no per-tap vmcnt(0) drains.
//  - Epilogue: acc -> LDS bounce [co][130] -> contiguous 504B/row dwordx2
//    streaming stores (fixes 1.31x partial-sector write amplification).
//  - XCD swizzle: each XCD owns 2 full batches -> halo set fits its 4MB L2.

#define BATCH 16
#define CIN   64
#define HIN   128
#define WIN   128
#define COUT  128
#define HO    126
#define WO    126

typedef short bf16x8 __attribute__((ext_vector_type(8)));
typedef float f32x4  __attribute__((ext_vector_type(4)));
typedef float f32x2  __attribute__((ext_vector_type(2)));

__device__ __forceinline__ unsigned short f2bf(float f) {
    union { float f; unsigned int u; } v; v.f = f;
    unsigned int u = v.u;
    unsigned int r = (u + 0x7fffu + ((u >> 16) & 1u)) >> 16;
    return (unsigned short)r;
}

// async global->LDS, 16B per lane. LDS dest = wave-uniform base + lane*16.
__device__ __forceinline__ void async16(const void* g, void* l) {
    __builtin_amdgcn_global_load_lds(
        (const __attribute__((address_space(1))) unsigned int*)(unsigned long long)g,
        (__attribute__((address_space(3))) unsigned int*)(unsigned long long)l,
        16, 0, 0);
}

// ---------- Pre-pass 1: NCHW fp32 -> NHWC bf16 ----------
__global__ __launch_bounds__(256) void t1_nchw_to_nhwc(
        const float* __restrict__ x, unsigned short* __restrict__ y) {
    __shared__ unsigned short tile[64 * 68]; // [w][ci], pad 68 keeps 8B align
    const int b = blockIdx.z, h = blockIdx.y, w0 = blockIdx.x * 64;
    const int t = threadIdx.x;

    const int wl = t & 63, ci0 = t >> 6; // ci0 in 0..3
    const float* src = x + (((size_t)b * CIN) * HIN + h) * WIN + w0 + wl;
#pragma unroll
    for (int j = 0; j < 16; j++) {
        const int ci = ci0 + j * 4;
        tile[wl * 68 + ci] = f2bf(src[(size_t)ci * (HIN * WIN)]);
    }
    __syncthreads();

    const int ci4 = (t & 15) * 4, wl2 = t >> 4; // wl2 in 0..15
#pragma unroll
    for (int j = 0; j < 4; j++) {
        const int w = wl2 + j * 16;
        ushort4 v = *(const ushort4*)&tile[w * 68 + ci4];
        *(ushort4*)&y[(((size_t)b * HIN + h) * WIN + w0 + w) * CIN + ci4] = v;
    }
}

// ---------- Pre-pass 2: weights [co][ci][kh][kw] fp32 -> [kh*3+kw][co][ci] bf16 ----------
__global__ __launch_bounds__(256) void t2_weights(
        const float* __restrict__ w, unsigned short* __restrict__ wt) {
    const int idx = blockIdx.x * 256 + threadIdx.x;
    if (idx < COUT * CIN * 9) {
        const int co = idx / (CIN * 9);
        const int r  = idx % (CIN * 9);
        const int ci = r / 9;
        const int k  = r % 9;
        wt[((size_t)k * COUT + co) * CIN + ci] = f2bf(w[idx]);
    }
}

// ---------- Main: implicit-GEMM MFMA conv, full-width row tile ----------
// grid (126, 16), block 256 (4 waves, wm = wave&1 over co, wn = wave>>1 over ow).
__global__ __launch_bounds__(256, 2) void conv_mfma(
        const unsigned short* __restrict__ nhwc,   // [b][h][w][ci] bf16
        const unsigned short* __restrict__ wt,     // [tap][co][ci] bf16
        float* __restrict__ out) {
    // Halo Bs: [3*128 + 2 slack rows][64 ci] bf16 = 49,408 B, XOR-swizzled.
    // Epilogue bounce Cb aliases the same LDS: [64 co'][130] f32 = 33,280 B.
    __shared__ __align__(16) char smem[49408];
    short* Bs = (short*)smem;
    float* Cb = (float*)smem;

    // XCD swizzle: nwg=2016, 2016%8==0 -> simple bijective chunking.
    // Each XCD gets 252 consecutive (b,oh) = 2 full batches -> L2-local halo.
    const int raw = blockIdx.y * 126 + blockIdx.x;
    const int s = (raw & 7) * 252 + (raw >> 3);
    const int b = s / 126;
    const int oh = s - b * 126;

    const int tid = threadIdx.x;
    const int lane = tid & 63, wave = tid >> 6;
    const int wm = wave & 1, wn = wave >> 1;
    const int col = lane & 15, quad = lane >> 4;
    // staging-side pre-swizzle: LDS linear byte L holds global byte
    // L ^ ((row&7)<<4), rows are 128 B. Valid for any 1KB-aligned chunk.
    const int swl = (lane * 16) ^ ((lane >> 3) << 4);

    // Prologue: stage the 48KB halo (rows oh..oh+2, contiguous in NHWC).
    {
        const char* src = (const char*)nhwc + (size_t)(b * HIN + oh) * (WIN * CIN * 2);
        char* dst = (char*)Bs;
#pragma unroll
        for (int i = 0; i < 12; i++) {
            const int c = wave * 12 + i;
            async16(src + c * 1024 + swl, dst + c * 1024 + lane * 16);
        }
    }

    // A fragments straight from global into registers (weights are L2-hot).
    // index (t, mi, kk): (t*COUT + wm*64 + mi*16 + col)*CIN + kk*32 + quad*8
    const unsigned short* wbase = wt + (size_t)(wm * 64 + col) * CIN + quad * 8;

#define LOADA(dst, t) do {                                                   \
    _Pragma("unroll") for (int mi_ = 0; mi_ < 4; mi_++)                      \
    _Pragma("unroll") for (int kk_ = 0; kk_ < 2; kk_++)                      \
        dst[mi_][kk_] = *(const bf16x8*)(wbase +                             \
            ((t) * COUT + mi_ * 16) * CIN + kk_ * 32);                       \
} while (0)

    bf16x8 aA[4][2], aB[4][2];
    LOADA(aA, 0);

    __syncthreads(); // halo visible (compiler drains vmcnt before barrier)

    f32x4 acc[4][4] = {};

    // Barrier-free 9-tap K-loop; t is compile-time (full unroll) so the
    // aA/aB ping-pong is static (no dynamic reg indexing).
#pragma unroll
    for (int t = 0; t < 9; t++) {
        const int kh = t / 3, kw = t - kh * 3;
        if (t + 1 < 9) {
            if (t & 1) LOADA(aA, t + 1); else LOADA(aB, t + 1);
        }
#pragma unroll
        for (int kk = 0; kk < 2; kk++) {
            bf16x8 bb[4];
#pragma unroll
            for (int ni = 0; ni < 4; ni++) {
                const int r = kh * 128 + wn * 64 + ni * 16 + col + kw;
                bb[ni] = *(const bf16x8*)&Bs[(r * 64 + kk * 32 + quad * 8) ^ ((r & 7) << 3)];
            }
#pragma unroll
            for (int mi = 0; mi < 4; mi++)
#pragma unroll
                for (int ni = 0; ni < 4; ni++)
                    acc[mi][ni] = __builtin_amdgcn_mfma_f32_16x16x32_bf16(
                        (t & 1) ? aB[mi][kk] : aA[mi][kk], bb[ni], acc[mi][ni], 0, 0, 0);
        }
    }
    // Lanes with n>=126 consumed stale LDS (rows 384..385 slack) -> garbage
    // stays in those lanes' acc columns only; never stored below.

    // Epilogue: two co-halves through LDS bounce, then streaming stores.
    // Each (b,co,oh) output row is 504 B contiguous; lane l stores ow {2l,2l+1}
    // as dwordx2 (rows are 8B-aligned: 504 % 8 == 0). Full-line streaming.
#pragma unroll
    for (int h = 0; h < 2; h++) {
        __syncthreads(); // h=0: done reading Bs; h=1: done reading Cb half 0
        if (wm == h) {
#pragma unroll
            for (int mi = 0; mi < 4; mi++)
#pragma unroll
                for (int ni = 0; ni < 4; ni++) {
                    const int n = wn * 64 + ni * 16 + col;
#pragma unroll
                    for (int r = 0; r < 4; r++)
                        Cb[(mi * 16 + quad * 4 + r) * 130 + n] = acc[mi][ni][r];
                }
        }
        __syncthreads();
        if (lane < 63) {
#pragma unroll
            for (int j = 0; j < 16; j++) {
                const int cp = wave * 16 + j; // co' 0..63 within this half
                f32x2 v = *(const f32x2*)&Cb[cp * 130 + lane * 2];
                float* o = out + (((size_t)b * COUT + h * 64 + cp) * HO + oh) * WO + lane * 2;
                *(f32x2*)o = v;
            }
        }
    }
}

// ---------- Fallback: direct fp32 conv (if d_ws too small) ----------
__global__ __launch_bounds__(256) void conv_direct(
        const float* __restrict__ x, const float* __restrict__ w,
        float* __restrict__ y) {
    const int idx = blockIdx.x * 256 + threadIdx.x;
    if (idx >= BATCH * COUT * HO * WO) return;
    const int ow = idx % WO;
    int t = idx / WO;
    const int oh = t % HO; t /= HO;
    const int co = t % COUT;
    const int b  = t / COUT;
    float acc = 0.f;
    const float* xb = x + (((size_t)b * CIN) * HIN + oh) * WIN + ow;
    const float* wc = w + (size_t)co * (CIN * 9);
    for (int ci = 0; ci < CIN; ci++) {
#pragma unroll
        for (int kh = 0; kh < 3; kh++)
#pragma unroll
            for (int kw = 0; kw < 3; kw++)
                acc += xb[(size_t)ci * (HIN * WIN) + kh * WIN + kw] * wc[ci * 9 + kh * 3 + kw];
    }
    y[idx] = acc;
}

extern "C" void kernel_launch(void* const* d_in, const int* in_sizes, int n_in,
                              void* d_out, int out_size, void* d_ws, size_t ws_size,
                              hipStream_t stream) {
    const float* data    = (const float*)d_in[0];
    const float* weights = (const float*)d_in[1];
    float* out = (float*)d_out;

    const size_t nhwc_bytes = (size_t)BATCH * HIN * WIN * CIN * 2; // 32 MiB
    const size_t slack = 4096;
    const size_t wt_bytes = (size_t)9 * COUT * CIN * 2;            // 144 KiB
    const size_t need = nhwc_bytes + slack + wt_bytes;

    if (ws_size >= need) {
        unsigned short* nhwc = (unsigned short*)d_ws;
        unsigned short* wt   = (unsigned short*)((char*)d_ws + nhwc_bytes + slack);
        t1_nchw_to_nhwc<<<dim3(2, HIN, BATCH), 256, 0, stream>>>(data, nhwc);
        t2_weights<<<(COUT * CIN * 9 + 255) / 256, 256, 0, stream>>>(weights, wt);
        conv_mfma<<<dim3(126, BATCH), 256, 0, stream>>>(nhwc, wt, out);
    } else {
        const int n = BATCH * COUT * HO * WO;
        conv_direct<<<(n + 255) / 256, 256, 0, stream>>>(data, weights, out);
    }
}